// Round 10
// baseline (148.090 us; speedup 1.0000x reference)
//
#include <hip/hip_runtime.h>
#include <stdint.h>

// Flash attention fwd, B=16, L=2048, D=128, fp32 in/out.
// R17: kv-split=1 -> combine kernel ELIMINATED. R16 postmortem: attn dur
// invariant to occupancy (4/8/12 waves all ~45-47us; LDS-port+phase bound);
// the cheap win is the pipeline: combine (~11us) exists only for kv-split.
// attnF = R15's proven per-wave code (32x32 MFMA, in-reg P via cvt_pk+
// permlane32_swap, granule-major conflict-free LDS, 0 conflicts measured,
// single-buffered 2-barrier cadence) reshaped to:
//  - 128-thr blocks (2 waves x 32q = 64 q rows), grid 512 = 16b x 32qblk
//    -> 2 independent blocks/CU (phase drift preserved), 4 waves/CU,
//    identical per-CU port/MFMA load to R15's measured 44.7us.
//  - nt=32 (full kv sweep per block), lrun accumulates all tiles.
//  - epilogue: l = own+partner, iv=1/l in-register, direct fp32 O stores
//    (lane owns full d-rows for q=q32; d = dt*32+hi*4+jj*8+e, the
//    combineR-verified mapping). No partials, no lsum, no transpose.
// WS: kb 8.4M | vt 8.4M = 16.8 MB only.

typedef short bf16x8 __attribute__((ext_vector_type(8)));
typedef float f32x16 __attribute__((ext_vector_type(16)));
typedef unsigned int u32;
typedef unsigned short u16;

#define L_SEQ  2048
#define D_HEAD 128
#define TSZ    8388608u                          // bytes per bf16 tensor

__device__ __forceinline__ unsigned pk2(float lo, float hi) {
    union { float f; unsigned u; } a, b;
    a.f = lo; b.f = hi;
    return __builtin_amdgcn_perm(b.u + 0x8000u, a.u + 0x8000u, 0x07060302u);
}
__device__ __forceinline__ float ex2(float x) { return __builtin_amdgcn_exp2f(x); }
__device__ __forceinline__ u32 cvtpk(float lo, float hi) {
    u32 d;
    asm("v_cvt_pk_bf16_f32 %0, %1, %2" : "=v"(d) : "v"(lo), "v"(hi));
    return d;
}
__device__ __forceinline__ void plswap(u32& a, u32& b) {
    asm volatile("v_permlane32_swap_b32 %0, %1" : "+v"(a), "+v"(b));
}
__device__ __forceinline__ void gl_lds16(const u16* g, u16* l) {
    __builtin_amdgcn_global_load_lds(
        (const __attribute__((address_space(1))) u32*)g,
        (__attribute__((address_space(3))) u32*)l, 16, 0, 0);
}

// ---------------- pre-pass: granule-major outputs (R15/R16, proven) --------
// wg 0..511:  K tile id -> kb[id][g=0..15][r=0..63][8] bf16
// wg 512..1023: V tile -> vt[id][gv=0..7][d=0..127][8 kv] bf16 (V^T)
__global__ __launch_bounds__(256, 4)
void prepass(const float* __restrict__ K, const float* __restrict__ V,
             u16* __restrict__ kb, u16* __restrict__ vt) {
    const int id = blockIdx.x, t = threadIdx.x;
    if (id < 512) {
        const float* src = K + (size_t)id * 64 * 128;
        u16*        dst = kb + (size_t)id * 64 * 128;
        const int r = t >> 2;
        #pragma unroll
        for (int i = 0; i < 4; ++i) {
            int gp = (t & 3) * 4 + i;              // logical granule 0..15
            const float* s = src + r * 128 + gp * 8;
            float4 x0 = *(const float4*)s, x1 = *(const float4*)(s + 4);
            uint4 w;
            w.x = pk2(x0.x, x0.y); w.y = pk2(x0.z, x0.w);
            w.z = pk2(x1.x, x1.y); w.w = pk2(x1.z, x1.w);
            *(uint4*)(dst + (gp * 64 + r) * 8) = w;   // granule-major
        }
    } else {
        // V^T: register 8x4 transpose -> vl rows (stride 72) -> [gv][d] store
        __shared__ __align__(16) u16 vl[128 * 72];
        const int bid = id - 512;
        const float* src = V + (size_t)bid * 64 * 128;
        const int vcc = t & 31, vgk = t >> 5;
        union { float4 v; float f[4]; } vr[8];
        const float* vp = src + (size_t)(vgk * 8) * 128 + vcc * 4;
        #pragma unroll
        for (int r = 0; r < 8; ++r) vr[r].v = *(const float4*)(vp + (size_t)r * 128);
        #pragma unroll
        for (int dd = 0; dd < 4; ++dd) {
            uint4 w;
            w.x = pk2(vr[0].f[dd], vr[1].f[dd]);
            w.y = pk2(vr[2].f[dd], vr[3].f[dd]);
            w.z = pk2(vr[4].f[dd], vr[5].f[dd]);
            w.w = pk2(vr[6].f[dd], vr[7].f[dd]);
            *(uint4*)(&vl[(vcc * 4 + dd) * 72 + vgk * 8]) = w;
        }
        __syncthreads();
        u16* dst = vt + (size_t)bid * 8192;
        #pragma unroll
        for (int i = 0; i < 4; ++i) {
            int c = i * 256 + t;                   // chunk = gv*128 + d
            int gv = c >> 7, d = c & 127;
            uint4 w = *(const uint4*)(&vl[d * 72 + gv * 8]);
            *(uint4*)(dst + (size_t)c * 8) = w;    // coalesced store
        }
    }
}

// ---------------- main kernel: full kv sweep, direct O ---------------------
// LDS: Kbuf 0..16K ([g][row][8]), Vbuf 16K..32K ([gv][d][8]). No P buffer.
__global__ __launch_bounds__(128, 2)
void attnF(const float* __restrict__ Qg, const u16* __restrict__ kb,
           const u16* __restrict__ vt, float* __restrict__ Og) {
    __shared__ __align__(16) char smem[32768];
    const int tid = threadIdx.x;
    const int qs = tid >> 6, lane = tid & 63;
    const int q32 = lane & 31, hi = lane >> 5;
    const int p = blockIdx.x;
    const int b = p & 15, qblk = p >> 4;           // 64 q rows per block
    const int nt = 32;

    const float* Qp = Qg + (size_t)b * L_SEQ * D_HEAD;
    const u16*   Kp = kb + (size_t)b * L_SEQ * D_HEAD;
    const u16*   Vp = vt + (size_t)b * 32 * 8192;
    u16* Kl = (u16*)smem;
    u16* Vl = (u16*)(smem + 16384);
    const int so = tid * 8;                        // DMA offset, u16 units

    #pragma unroll
    for (int i = 0; i < 8; ++i) {
        gl_lds16(Kp + so + i * 1024, Kl + so + i * 1024);
        gl_lds16(Vp + so + i * 1024, Vl + so + i * 1024);
    }

    // Q fragments: lane provides col=q32, k = s8*16 + hi*8 + {0..7}
    const float QS = 1.4426950408889634f / 11.313708498984761f; // log2e/sqrt(128)
    bf16x8 qf[8];
    {
        const float* qrow = Qp + (size_t)(qblk * 64 + qs * 32 + q32) * 128 + hi * 8;
        #pragma unroll
        for (int s8 = 0; s8 < 8; ++s8) {
            float4 x0 = *(const float4*)(qrow + s8 * 16);
            float4 x1 = *(const float4*)(qrow + s8 * 16 + 4);
            union { u32 u[4]; bf16x8 v; } tt;
            tt.u[0] = pk2(x0.x * QS, x0.y * QS);
            tt.u[1] = pk2(x0.z * QS, x0.w * QS);
            tt.u[2] = pk2(x1.x * QS, x1.y * QS);
            tt.u[3] = pk2(x1.z * QS, x1.w * QS);
            qf[s8] = tt.v;
        }
    }

    f32x16 acc[4];
    #pragma unroll
    for (int dt = 0; dt < 4; ++dt)
        acc[dt] = (f32x16){0.f,0.f,0.f,0.f,0.f,0.f,0.f,0.f,
                           0.f,0.f,0.f,0.f,0.f,0.f,0.f,0.f};
    float lrun = 0.f;

    __syncthreads();   // tile 0 staged (implicit vmcnt drain)

    for (int it = 0; it < nt; ++it) {
        // ---- S^T(64kv x 32q) = K.Q^T, two 32x32 tiles; conflict-free reads
        f32x16 st0 = (f32x16){0.f,0.f,0.f,0.f,0.f,0.f,0.f,0.f,
                              0.f,0.f,0.f,0.f,0.f,0.f,0.f,0.f};
        f32x16 st1 = st0;
        const u16* Kbase = Kl + hi * 512 + q32 * 8;
        #pragma unroll
        for (int s8 = 0; s8 < 8; ++s8) {
            bf16x8 a0 = *(const bf16x8*)(Kbase + s8 * 1024);
            bf16x8 a1 = *(const bf16x8*)(Kbase + s8 * 1024 + 256);
            st0 = __builtin_amdgcn_mfma_f32_32x32x16_bf16(a0, qf[s8], st0, 0, 0, 0);
            st1 = __builtin_amdgcn_mfma_f32_32x32x16_bf16(a1, qf[s8], st1, 0, 0, 0);
        }
        __syncthreads();   // B1: K-reads done (both waves); V(it) DMA drained

        if (it + 1 < nt) {
            const u16* kg = Kp + (size_t)(it + 1) * 8192 + so;
            #pragma unroll
            for (int i = 0; i < 8; ++i) gl_lds16(kg + i * 1024, Kl + so + i * 1024);
        }

        // ---- softmax (sum-only) + pack P into PV B-fragments, in registers
        bf16x8 pf[4];
        #pragma unroll
        for (int v = 0; v < 2; ++v) {
            float pp[16];
            #pragma unroll
            for (int e = 0; e < 16; ++e) {
                float sv = (v == 0) ? st0[e] : st1[e];
                pp[e] = ex2(sv);
                lrun += pp[e];
            }
            u32 wa0 = cvtpk(pp[0], pp[1]),  wb0 = cvtpk(pp[4], pp[5]);
            u32 wa1 = cvtpk(pp[2], pp[3]),  wb1 = cvtpk(pp[6], pp[7]);
            plswap(wa0, wb0); plswap(wa1, wb1);
            u32 wc0 = cvtpk(pp[8], pp[9]),  wd0 = cvtpk(pp[12], pp[13]);
            u32 wc1 = cvtpk(pp[10], pp[11]), wd1 = cvtpk(pp[14], pp[15]);
            plswap(wc0, wd0); plswap(wc1, wd1);
            union { u32 u[4]; bf16x8 x; } t0u, t1u;
            t0u.u[0] = wa0; t0u.u[1] = wa1; t0u.u[2] = wb0; t0u.u[3] = wb1;
            t1u.u[0] = wc0; t1u.u[1] = wc1; t1u.u[2] = wd0; t1u.u[3] = wd1;
            pf[v * 2]     = t0u.x;                 // kv v*32 + [0,16)
            pf[v * 2 + 1] = t1u.x;                 // kv v*32 + [16,32)
        }

        // ---- O^T += V^T.P^T  (full d=128, 4 d-tiles x 4 k-steps)
        const u16* Vbase = Vl + hi * 1024 + q32 * 8;
        #pragma unroll
        for (int dt = 0; dt < 4; ++dt) {
            #pragma unroll
            for (int ks = 0; ks < 4; ++ks) {
                bf16x8 av = *(const bf16x8*)(Vbase + ks * 2048 + dt * 256);
                acc[dt] = __builtin_amdgcn_mfma_f32_32x32x16_bf16(av, pf[ks], acc[dt], 0, 0, 0);
            }
        }
        __syncthreads();   // B2: V-reads done; K(it+1) DMA drained

        if (it + 1 < nt) {
            const u16* vg = Vp + (size_t)(it + 1) * 8192 + so;
            #pragma unroll
            for (int i = 0; i < 8; ++i) gl_lds16(vg + i * 1024, Vl + so + i * 1024);
        }
    }

    // ---- epilogue: l = own + partner half; O = acc/l, direct fp32 stores
    // d mapping (combineR-verified): d = dt*32 + hi*4 + jj*8 + e, e=0..3
    float l = lrun + __shfl_xor(lrun, 32);
    float iv = 1.0f / l;
    float* orow = Og + ((size_t)b * L_SEQ + qblk * 64 + qs * 32 + q32) * 128;
    #pragma unroll
    for (int dt = 0; dt < 4; ++dt) {
        #pragma unroll
        for (int jj = 0; jj < 4; ++jj) {
            float4 w;
            w.x = acc[dt][jj * 4 + 0] * iv;
            w.y = acc[dt][jj * 4 + 1] * iv;
            w.z = acc[dt][jj * 4 + 2] * iv;
            w.w = acc[dt][jj * 4 + 3] * iv;
            *(float4*)(orow + dt * 32 + hi * 4 + jj * 8) = w;
        }
    }
}

extern "C" void kernel_launch(void* const* d_in, const int* in_sizes, int n_in,
                              void* d_out, int out_size, void* d_ws, size_t ws_size,
                              hipStream_t stream) {
    const float* q = (const float*)d_in[0];
    const float* k = (const float*)d_in[1];
    const float* v = (const float*)d_in[2];
    float* out = (float*)d_out;
    u16* kb = (u16*)d_ws;
    u16* vt = (u16*)((char*)d_ws + TSZ);
    prepass<<<dim3(1024), dim3(256), 0, stream>>>(k, v, kb, vt);
    attnF<<<dim3(512), dim3(128), 0, stream>>>(q, kb, vt, out);
}

// Round 11
// 134.137 us; speedup vs baseline: 1.1040x; 1.1040x over previous
//
#include <hip/hip_runtime.h>
#include <stdint.h>

// Flash attention fwd, B=16, L=2048, D=128, fp32 in/out.
// R18: exact revert to R15 (best measured: total 132.76us, attn 44.7us,
// 0 bank conflicts) + s_setprio(1) around the QK and PV MFMA clusters (T5).
// R17 postmortem: wave-count curve 68.5us@4w / 44.7@8w / 46.9@12w -> 8
// waves/CU (2 independent 256-thr blocks) is the knee; R15 config optimal.
// Remaining deficit is pipe-overlap (LDS 20.5 + MFMA 13.4 + VALU 10.6 vs
// 44.7 measured); T5 biases the CU scheduler toward MFMA-phase waves while
// the co-resident block is in softmax (measured +4-7% in exactly this
// independent-block drifting-phase regime).
// WS: kb 8.4M | vt 8.4M | part 512x32K=16.8M | lsum 256K = 33.8 MB.

typedef short bf16x8 __attribute__((ext_vector_type(8)));
typedef float f32x4 __attribute__((ext_vector_type(4)));
typedef float f32x16 __attribute__((ext_vector_type(16)));
typedef unsigned int u32;
typedef unsigned short u16;

#define L_SEQ  2048
#define D_HEAD 128
#define TSZ    8388608u                          // bytes per bf16 tensor
#define W_PART (2u * TSZ)                        // 512 x 32 KB partials
#define W_LSUM (W_PART + 512u * 32768u)
#define WS_NEED (W_LSUM + 512u * 128u * 4u)

__device__ __forceinline__ unsigned pk2(float lo, float hi) {
    union { float f; unsigned u; } a, b;
    a.f = lo; b.f = hi;
    return __builtin_amdgcn_perm(b.u + 0x8000u, a.u + 0x8000u, 0x07060302u);
}
__device__ __forceinline__ float ex2(float x) { return __builtin_amdgcn_exp2f(x); }
__device__ __forceinline__ float bflo(unsigned w) {
    union { unsigned u; float f; } v; v.u = w << 16; return v.f;
}
__device__ __forceinline__ float bfhi(unsigned w) {
    union { unsigned u; float f; } v; v.u = w & 0xffff0000u; return v.f;
}
__device__ __forceinline__ u32 cvtpk(float lo, float hi) {
    u32 d;
    asm("v_cvt_pk_bf16_f32 %0, %1, %2" : "=v"(d) : "v"(lo), "v"(hi));
    return d;
}
__device__ __forceinline__ void plswap(u32& a, u32& b) {
    asm volatile("v_permlane32_swap_b32 %0, %1" : "+v"(a), "+v"(b));
}
__device__ __forceinline__ void gl_lds16(const u16* g, u16* l) {
    __builtin_amdgcn_global_load_lds(
        (const __attribute__((address_space(1))) u32*)g,
        (__attribute__((address_space(3))) u32*)l, 16, 0, 0);
}

// ---------------- pre-pass: granule-major outputs (R15, proven) ------------
// wg 0..511:  K tile id -> kb[id][g=0..15][r=0..63][8] bf16
// wg 512..1023: V tile -> vt[id][gv=0..7][d=0..127][8 kv] bf16 (V^T)
__global__ __launch_bounds__(256, 4)
void prepass(const float* __restrict__ K, const float* __restrict__ V,
             u16* __restrict__ kb, u16* __restrict__ vt) {
    const int id = blockIdx.x, t = threadIdx.x;
    if (id < 512) {
        const float* src = K + (size_t)id * 64 * 128;
        u16*        dst = kb + (size_t)id * 64 * 128;
        const int r = t >> 2;
        #pragma unroll
        for (int i = 0; i < 4; ++i) {
            int gp = (t & 3) * 4 + i;              // logical granule 0..15
            const float* s = src + r * 128 + gp * 8;
            float4 x0 = *(const float4*)s, x1 = *(const float4*)(s + 4);
            uint4 w;
            w.x = pk2(x0.x, x0.y); w.y = pk2(x0.z, x0.w);
            w.z = pk2(x1.x, x1.y); w.w = pk2(x1.z, x1.w);
            *(uint4*)(dst + (gp * 64 + r) * 8) = w;   // granule-major
        }
    } else {
        // V^T: register 8x4 transpose -> vl rows (stride 72) -> [gv][d] store
        __shared__ __align__(16) u16 vl[128 * 72];
        const int bid = id - 512;
        const float* src = V + (size_t)bid * 64 * 128;
        const int vcc = t & 31, vgk = t >> 5;
        union { float4 v; float f[4]; } vr[8];
        const float* vp = src + (size_t)(vgk * 8) * 128 + vcc * 4;
        #pragma unroll
        for (int r = 0; r < 8; ++r) vr[r].v = *(const float4*)(vp + (size_t)r * 128);
        #pragma unroll
        for (int dd = 0; dd < 4; ++dd) {
            uint4 w;
            w.x = pk2(vr[0].f[dd], vr[1].f[dd]);
            w.y = pk2(vr[2].f[dd], vr[3].f[dd]);
            w.z = pk2(vr[4].f[dd], vr[5].f[dd]);
            w.w = pk2(vr[6].f[dd], vr[7].f[dd]);
            *(uint4*)(&vl[(vcc * 4 + dd) * 72 + vgk * 8]) = w;
        }
        __syncthreads();
        u16* dst = vt + (size_t)bid * 8192;
        #pragma unroll
        for (int i = 0; i < 4; ++i) {
            int c = i * 256 + t;                   // chunk = gv*128 + d
            int gv = c >> 7, d = c & 127;
            uint4 w = *(const uint4*)(&vl[d * 72 + gv * 8]);
            *(uint4*)(dst + (size_t)c * 8) = w;    // coalesced store
        }
    }
}

// ---------------- main kernel: 32x32 MFMA, in-register P -------------------
// LDS: Kbuf 0..16K ([g][row][8]), Vbuf 16K..32K ([gv][d][8]). No P buffer.
__global__ __launch_bounds__(256, 2)
void attnR(const float* __restrict__ Qg, const u16* __restrict__ kb,
           const u16* __restrict__ vt, u16* __restrict__ part,
           float* __restrict__ lsum) {
    __shared__ __align__(16) char smem[32768];
    const int tid = threadIdx.x;
    const int qs = tid >> 6, lane = tid & 63;
    const int q32 = lane & 31, hi = lane >> 5;
    const int bid = blockIdx.x;
    const int kvh = bid >> 8, p = bid & 255;       // kvh in {0,1}
    const int b = p & 15, qblk = p >> 4;           // 128 q rows per block
    const int nt = 16;

    const float* Qp = Qg + (size_t)b * L_SEQ * D_HEAD;
    const u16*   Kp = kb + (size_t)b * L_SEQ * D_HEAD + (size_t)kvh * 16 * 8192;
    const u16*   Vp = vt + (size_t)b * 32 * 8192 + (size_t)kvh * 16 * 8192;
    u16* Kl = (u16*)smem;
    u16* Vl = (u16*)(smem + 16384);
    const int so = qs * 2048 + lane * 8;           // DMA offset, u16 units

    #pragma unroll
    for (int i = 0; i < 4; ++i) {
        gl_lds16(Kp + so + i * 512, Kl + so + i * 512);
        gl_lds16(Vp + so + i * 512, Vl + so + i * 512);
    }

    // Q fragments: lane provides col=q32, k = s8*16 + hi*8 + {0..7}
    const float QS = 1.4426950408889634f / 11.313708498984761f; // log2e/sqrt(128)
    bf16x8 qf[8];
    {
        const float* qrow = Qp + (size_t)(qblk * 128 + qs * 32 + q32) * 128 + hi * 8;
        #pragma unroll
        for (int s8 = 0; s8 < 8; ++s8) {
            float4 x0 = *(const float4*)(qrow + s8 * 16);
            float4 x1 = *(const float4*)(qrow + s8 * 16 + 4);
            union { u32 u[4]; bf16x8 v; } tt;
            tt.u[0] = pk2(x0.x * QS, x0.y * QS);
            tt.u[1] = pk2(x0.z * QS, x0.w * QS);
            tt.u[2] = pk2(x1.x * QS, x1.y * QS);
            tt.u[3] = pk2(x1.z * QS, x1.w * QS);
            qf[s8] = tt.v;
        }
    }

    f32x16 acc[4];
    #pragma unroll
    for (int dt = 0; dt < 4; ++dt)
        acc[dt] = (f32x16){0.f,0.f,0.f,0.f,0.f,0.f,0.f,0.f,
                           0.f,0.f,0.f,0.f,0.f,0.f,0.f,0.f};
    float lrun = 0.f;

    __syncthreads();   // tile 0 staged (implicit vmcnt drain)

    for (int it = 0; it < nt; ++it) {
        // ---- S^T(64kv x 32q) = K.Q^T, two 32x32 tiles; conflict-free reads
        f32x16 st0 = (f32x16){0.f,0.f,0.f,0.f,0.f,0.f,0.f,0.f,
                              0.f,0.f,0.f,0.f,0.f,0.f,0.f,0.f};
        f32x16 st1 = st0;
        const u16* Kbase = Kl + hi * 512 + q32 * 8;
        __builtin_amdgcn_s_setprio(1);             // T5: favor MFMA-phase wave
        #pragma unroll
        for (int s8 = 0; s8 < 8; ++s8) {
            bf16x8 a0 = *(const bf16x8*)(Kbase + s8 * 1024);
            bf16x8 a1 = *(const bf16x8*)(Kbase + s8 * 1024 + 256);
            st0 = __builtin_amdgcn_mfma_f32_32x32x16_bf16(a0, qf[s8], st0, 0, 0, 0);
            st1 = __builtin_amdgcn_mfma_f32_32x32x16_bf16(a1, qf[s8], st1, 0, 0, 0);
        }
        __builtin_amdgcn_s_setprio(0);
        __syncthreads();   // B1: K-reads done (all waves); V(it) DMA drained

        if (it + 1 < nt) {
            const u16* kg = Kp + (size_t)(it + 1) * 8192 + so;
            #pragma unroll
            for (int i = 0; i < 4; ++i) gl_lds16(kg + i * 512, Kl + so + i * 512);
        }

        // ---- softmax (sum-only) + pack P into PV B-fragments, in registers
        bf16x8 pf[4];
        #pragma unroll
        for (int v = 0; v < 2; ++v) {
            float pp[16];
            #pragma unroll
            for (int e = 0; e < 16; ++e) {
                float sv = (v == 0) ? st0[e] : st1[e];
                pp[e] = ex2(sv);
                lrun += pp[e];
            }
            u32 wa0 = cvtpk(pp[0], pp[1]),  wb0 = cvtpk(pp[4], pp[5]);
            u32 wa1 = cvtpk(pp[2], pp[3]),  wb1 = cvtpk(pp[6], pp[7]);
            plswap(wa0, wb0); plswap(wa1, wb1);
            u32 wc0 = cvtpk(pp[8], pp[9]),  wd0 = cvtpk(pp[12], pp[13]);
            u32 wc1 = cvtpk(pp[10], pp[11]), wd1 = cvtpk(pp[14], pp[15]);
            plswap(wc0, wd0); plswap(wc1, wd1);
            union { u32 u[4]; bf16x8 x; } t0u, t1u;
            t0u.u[0] = wa0; t0u.u[1] = wa1; t0u.u[2] = wb0; t0u.u[3] = wb1;
            t1u.u[0] = wc0; t1u.u[1] = wc1; t1u.u[2] = wd0; t1u.u[3] = wd1;
            pf[v * 2]     = t0u.x;                 // kv v*32 + [0,16)
            pf[v * 2 + 1] = t1u.x;                 // kv v*32 + [16,32)
        }

        // ---- O^T += V^T.P^T  (full d=128, 4 d-tiles x 4 k-steps)
        const u16* Vbase = Vl + hi * 1024 + q32 * 8;
        __builtin_amdgcn_s_setprio(1);             // T5
        #pragma unroll
        for (int dt = 0; dt < 4; ++dt) {
            #pragma unroll
            for (int ks = 0; ks < 4; ++ks) {
                bf16x8 av = *(const bf16x8*)(Vbase + ks * 2048 + dt * 256);
                acc[dt] = __builtin_amdgcn_mfma_f32_32x32x16_bf16(av, pf[ks], acc[dt], 0, 0, 0);
            }
        }
        __builtin_amdgcn_s_setprio(0);
        __syncthreads();   // B2: V-reads done; K(it+1) DMA drained

        if (it + 1 < nt) {
            const u16* vg = Vp + (size_t)(it + 1) * 8192 + so;
            #pragma unroll
            for (int i = 0; i < 4; ++i) gl_lds16(vg + i * 512, Vl + so + i * 512);
        }
    }

    // ---- epilogue: l = own + partner half; store bf16 O^T partial + l
    float l = lrun + __shfl_xor(lrun, 32);
    uint2* pw = (uint2*)(part + (size_t)bid * 16384);
    #pragma unroll
    for (int dt = 0; dt < 4; ++dt) {
        f32x16 o = acc[dt];
        #pragma unroll
        for (int jj = 0; jj < 4; ++jj) {
            uint2 w;
            w.x = pk2(o[jj * 4 + 0], o[jj * 4 + 1]);
            w.y = pk2(o[jj * 4 + 2], o[jj * 4 + 3]);
            pw[(((qs * 4 + dt) * 4 + jj) << 6) + lane] = w;
        }
    }
    if (lane < 32)
        lsum[(size_t)bid * 128 + qs * 32 + lane] = l;
}

// ---------------- combine: O = (O0+O1)/l, transpose, store -----------------
// partial word (qs,dt,jj,lane): q = qs*32+(lane&31),
// d = dt*32 + 4*(lane>>5) + 8*jj + {0..3} (x:0,1  y:2,3)
__global__ __launch_bounds__(256, 2)
void combineR(const u16* __restrict__ part, const float* __restrict__ lsum,
              float* __restrict__ Og) {
    __shared__ float inv[128];
    __shared__ __align__(16) float Ol[64 * 132];
    const int t = threadIdx.x, p = blockIdx.x;
    const int b = p & 15, qblk = p >> 4;
    if (t < 128) {
        float l = lsum[(size_t)p * 128 + t] + lsum[(size_t)(256 + p) * 128 + t];
        inv[t] = 1.0f / l;
    }
    const uint2* S0 = (const uint2*)(part + (size_t)p * 16384);
    const uint2* S1 = (const uint2*)(part + (size_t)(256 + p) * 16384);
    __syncthreads();
    #pragma unroll
    for (int h = 0; h < 2; ++h) {                  // q-strip pairs
        #pragma unroll
        for (int i = 0; i < 8; ++i) {
            int slot = i * 256 + t;                // 0..2047
            int qs_l = slot >> 10;
            int dt   = (slot >> 8) & 3;
            int jj   = (slot >> 6) & 3;
            int lane = slot & 63;
            int hi = lane >> 5, q32 = lane & 31;
            int qs = h * 2 + qs_l;
            int row_l = qs_l * 32 + q32;           // 0..63
            int d0 = dt * 32 + hi * 4 + jj * 8;
            size_t idx = (size_t)(((qs * 4 + dt) * 4 + jj) << 6) + lane;
            uint2 w0 = S0[idx], w1 = S1[idx];
            float iv = inv[h * 64 + row_l];
            float4 o;
            o.x = (bflo(w0.x) + bflo(w1.x)) * iv;
            o.y = (bfhi(w0.x) + bfhi(w1.x)) * iv;
            o.z = (bflo(w0.y) + bflo(w1.y)) * iv;
            o.w = (bfhi(w0.y) + bfhi(w1.y)) * iv;
            *(float4*)(&Ol[row_l * 132 + d0]) = o;
        }
        __syncthreads();
        #pragma unroll
        for (int i = 0; i < 8; ++i) {
            int slot = i * 256 + t;
            int row = slot >> 5, c4 = slot & 31;
            float4 val = *(const float4*)(&Ol[row * 132 + c4 * 4]);
            size_t q = (size_t)b * L_SEQ + qblk * 128 + h * 64 + row;
            *(float4*)(Og + q * D_HEAD + c4 * 4) = val;
        }
        __syncthreads();
    }
}

extern "C" void kernel_launch(void* const* d_in, const int* in_sizes, int n_in,
                              void* d_out, int out_size, void* d_ws, size_t ws_size,
                              hipStream_t stream) {
    const float* q = (const float*)d_in[0];
    const float* k = (const float*)d_in[1];
    const float* v = (const float*)d_in[2];
    float* out = (float*)d_out;
    u16* kb = (u16*)d_ws;
    u16* vt = (u16*)((char*)d_ws + TSZ);
    u16* part = (u16*)((char*)d_ws + W_PART);
    float* ls = (float*)((char*)d_ws + W_LSUM);
    prepass<<<dim3(1024), dim3(256), 0, stream>>>(k, v, kb, vt);
    attnR<<<dim3(512), dim3(256), 0, stream>>>(q, kb, vt, part, ls);
    combineR<<<dim3(256), dim3(256), 0, stream>>>(part, ls, out);
}